// Round 19
// baseline (722.272 us; speedup 1.0000x reference)
//
#include <hip/hip_runtime.h>
#include <hip/hip_bf16.h>
#include <math.h>

// ---------------------------------------------------------------------------
// Constants (problem-fixed)
// ---------------------------------------------------------------------------
static const int NNODES = 10240;
static const int NEDGES = 40960;
static const int NB     = 256;     // graphs / batch
static const int VOCAB  = 26;
static const int EMB    = 128;
static const int LP     = 128;     // padded t-length for NHC conv activations
static const int C1SPLIT = 8;      // conv1 phase-1 i-split (1000/8 = 125)

typedef short bf16x8 __attribute__((ext_vector_type(8)));   // 8 bf16 (4 VGPRs)
typedef float f32x4  __attribute__((ext_vector_type(4)));   // 4 fp32

__device__ __forceinline__ float bf16bits2float(short s) {
    return __uint_as_float(((unsigned)(unsigned short)s) << 16);
}

// ---------------------------------------------------------------------------
// reduce S slices + bias + relu -> C (ldC)  (MFMA split-K epilogue)
// ---------------------------------------------------------------------------
__global__ void reduce_bias_relu_ld_kernel(const float* __restrict__ P,
                                           const float* __restrict__ bias,
                                           float* __restrict__ C,
                                           int M, int N, int S, int ldC)
{
    int t = blockIdx.x * 256 + threadIdx.x;
    if (t >= M * N) return;
    int r = t / N, c = t - r * N;
    float v = bias[c];
    for (int s = 0; s < S; ++s) v += P[(size_t)s * M * N + t];
    C[(size_t)r * ldC + c] = fmaxf(v, 0.f);
}

// ---------------------------------------------------------------------------
// Fully fused FC head, 1024 threads/block (16 waves/CU).
// ---------------------------------------------------------------------------
__global__ __launch_bounds__(1024) void fused_head_kernel(
    const float* __restrict__ g1, const float* __restrict__ xt1,
    const float* __restrict__ fc_g2_w, const float* __restrict__ fc_g2_b,
    const float* __restrict__ fc2_xt_w, const float* __restrict__ fc2_xt_b,
    const float* __restrict__ fc1_w, const float* __restrict__ fc1_b,
    const float* __restrict__ fc2_w, const float* __restrict__ fc2_b,
    const float* __restrict__ out_w, const float* __restrict__ out_b,
    float* __restrict__ out)
{
    __shared__ float s_in[2048];   // g1 row | xt1 row
    __shared__ float s_part[1024];
    __shared__ float s_xc[256];
    __shared__ float s_f1[1024];
    __shared__ float s_f2[256];
    __shared__ float s_red[4];
    int r = blockIdx.x, t = threadIdx.x;
    for (int i = t; i < 2048; i += 1024)
        s_in[i] = (i < 1024) ? g1[(size_t)r * 1024 + i]
                             : xt1[(size_t)r * 1024 + (i - 1024)];
    __syncthreads();
    // phase A: xc; output c = t&255, K-quarter q = t>>8
    {
        int c = t & 255, q = t >> 8;
        const float* W  = (c < 128) ? fc_g2_w : fc2_xt_w;
        const float* in = (c < 128) ? s_in : s_in + 1024;
        int cc = c & 127;
        int k0 = q * 256;
        float a0 = 0.f, a1 = 0.f, a2 = 0.f, a3 = 0.f;
#pragma unroll 4
        for (int k = 0; k < 256; k += 4) {
            a0 += in[k0 + k + 0] * W[(size_t)(k0 + k + 0) * 128 + cc];
            a1 += in[k0 + k + 1] * W[(size_t)(k0 + k + 1) * 128 + cc];
            a2 += in[k0 + k + 2] * W[(size_t)(k0 + k + 2) * 128 + cc];
            a3 += in[k0 + k + 3] * W[(size_t)(k0 + k + 3) * 128 + cc];
        }
        s_part[t] = (a0 + a1) + (a2 + a3);
    }
    __syncthreads();
    if (t < 256) {
        const float* bb = (t < 128) ? fc_g2_b : fc2_xt_b;
        s_xc[t] = bb[t & 127] + (s_part[t] + s_part[t + 256])
                              + (s_part[t + 512] + s_part[t + 768]);
    }
    __syncthreads();
    // phase B: f1 col = t, K=256
    {
        float b0 = 0.f, b1 = 0.f, b2 = 0.f, b3 = 0.f;
#pragma unroll 4
        for (int k = 0; k < 256; k += 4) {
            b0 += s_xc[k + 0] * fc1_w[(size_t)(k + 0) * 1024 + t];
            b1 += s_xc[k + 1] * fc1_w[(size_t)(k + 1) * 1024 + t];
            b2 += s_xc[k + 2] * fc1_w[(size_t)(k + 2) * 1024 + t];
            b3 += s_xc[k + 3] * fc1_w[(size_t)(k + 3) * 1024 + t];
        }
        s_f1[t] = fmaxf(fc1_b[t] + ((b0 + b1) + (b2 + b3)), 0.f);
    }
    __syncthreads();
    // phase C: f2; output c = t&255, K-quarter q = t>>8
    {
        int c = t & 255, q = t >> 8;
        int k0 = q * 256;
        float c0 = 0.f, c1 = 0.f, c2 = 0.f, c3 = 0.f;
#pragma unroll 4
        for (int k = 0; k < 256; k += 4) {
            c0 += s_f1[k0 + k + 0] * fc2_w[(size_t)(k0 + k + 0) * 256 + c];
            c1 += s_f1[k0 + k + 1] * fc2_w[(size_t)(k0 + k + 1) * 256 + c];
            c2 += s_f1[k0 + k + 2] * fc2_w[(size_t)(k0 + k + 2) * 256 + c];
            c3 += s_f1[k0 + k + 3] * fc2_w[(size_t)(k0 + k + 3) * 256 + c];
        }
        s_part[t] = (c0 + c1) + (c2 + c3);
    }
    __syncthreads();
    if (t < 256)
        s_f2[t] = fmaxf(fc2_b[t] + (s_part[t] + s_part[t + 256])
                                 + (s_part[t + 512] + s_part[t + 768]), 0.f);
    __syncthreads();
    // phase D: out (first 4 waves)
    if (t < 256) {
        float p = s_f2[t] * out_w[t];
        for (int o = 32; o; o >>= 1) p += __shfl_down(p, o);
        if ((t & 63) == 0) s_red[t >> 6] = p;
    }
    __syncthreads();
    if (t == 0)
        out[r] = s_red[0] + s_red[1] + s_red[2] + s_red[3] + out_b[0];
}

// ---------------------------------------------------------------------------
// casts
// ---------------------------------------------------------------------------
__global__ void cast_a_kernel(const float* __restrict__ in, __hip_bfloat16* __restrict__ out,
                              int M, int K, int Kp)
{
    int idx = blockIdx.x * 256 + threadIdx.x;
    if (idx >= M * Kp) return;
    int r = idx / Kp, k = idx - r * Kp;
    out[idx] = __float2bfloat16(k < K ? in[(size_t)r * K + k] : 0.f);
}

__global__ __launch_bounds__(256) void transpose_cast_kernel(
    const float* __restrict__ in, __hip_bfloat16* __restrict__ out,
    int K, int N, int Kp, int Npad)
{
    __shared__ float tile[32][33];
    int k0 = blockIdx.x * 32;
    int n0 = blockIdx.y * 32;
    int tx = threadIdx.x & 31;
    int ty = threadIdx.x >> 5;
#pragma unroll
    for (int j = 0; j < 4; ++j) {
        int k = k0 + ty + j * 8, n = n0 + tx;
        tile[ty + j * 8][tx] = (k < K && n < N) ? in[(size_t)k * N + n] : 0.f;
    }
    __syncthreads();
#pragma unroll
    for (int j = 0; j < 4; ++j) {
        int n = n0 + ty + j * 8, k = k0 + tx;
        if (n < Npad && k < Kp)
            out[(size_t)n * Kp + k] = __float2bfloat16(tile[tx][ty + j * 8]);
    }
}

// merged conv weight prep: conv2/3/4 k-major bf16 + conv1 f32 transpose
__global__ void conv_wt_all_kernel(
    const float* __restrict__ cw2, const float* __restrict__ cw3,
    const float* __restrict__ cw4, const float* __restrict__ cw1,
    __hip_bfloat16* __restrict__ wt2, __hip_bfloat16* __restrict__ wt3,
    __hip_bfloat16* __restrict__ wt4, float* __restrict__ wt1f)
{
    int idx = blockIdx.x * 256 + threadIdx.x;
    const int n2 = 64 * 32 * 8, n3 = 96 * 64 * 8, n4 = 128 * 96 * 8;
    if (idx < n2) {
        int o = idx / (32 * 8), rem = idx - o * 32 * 8;
        int i = rem >> 3, k = rem & 7;
        wt2[(size_t)o * 256 + k * 32 + i] = __float2bfloat16(cw2[idx]);
    } else if (idx < n2 + n3) {
        int j = idx - n2;
        int o = j / (64 * 8), rem = j - o * 64 * 8;
        int i = rem >> 3, k = rem & 7;
        wt3[(size_t)o * 512 + k * 64 + i] = __float2bfloat16(cw3[j]);
    } else if (idx < n2 + n3 + n4) {
        int j = idx - n2 - n3;
        int o = j / (96 * 8), rem = j - o * 96 * 8;
        int i = rem >> 3, k = rem & 7;
        wt4[(size_t)o * 768 + k * 96 + i] = __float2bfloat16(cw4[j]);
    } else {
        int j = idx - n2 - n3 - n4;
        if (j >= 32 * 8000) return;
        int o = j / 8000, rem = j - o * 8000;
        int i = rem >> 3, k = rem & 7;
        wt1f[(size_t)i * 256 + o * 8 + k] = cw1[j];
    }
}

// ---------------------------------------------------------------------------
// Shared MFMA staging
// ---------------------------------------------------------------------------
__device__ __forceinline__ void stage_tile(
    const __hip_bfloat16* __restrict__ gA, int ldA,
    const __hip_bfloat16* __restrict__ gB, int ldB,
    short* ldsbuf, int w, int l)
{
#pragma unroll
    for (int j = 0; j < 4; ++j) {
        int u = (w * 4 + j) * 64 + l;
        int r = u >> 3, s = u & 7;
        const __hip_bfloat16* src = gA + (size_t)r * ldA + ((s ^ (r & 7)) << 3);
        __builtin_amdgcn_global_load_lds(
            (const __attribute__((address_space(1))) void*)src,
            (__attribute__((address_space(3))) void*)(ldsbuf + (w * 4 + j) * 512),
            16, 0, 0);
    }
#pragma unroll
    for (int j = 0; j < 4; ++j) {
        int u = (w * 4 + j) * 64 + l;
        int r = u >> 3, s = u & 7;
        const __hip_bfloat16* src = gB + (size_t)r * ldB + ((s ^ (r & 7)) << 3);
        __builtin_amdgcn_global_load_lds(
            (const __attribute__((address_space(1))) void*)src,
            (__attribute__((address_space(3))) void*)(ldsbuf + 8192 + (w * 4 + j) * 512),
            16, 0, 0);
    }
}

// ---------------------------------------------------------------------------
// MFMA bf16 GEMM (FC form), bf16 output, XCD-bijective block swizzle (m204).
// ---------------------------------------------------------------------------
__global__ __launch_bounds__(256, 2) void gemm_mfma_bf16(
    const __hip_bfloat16* __restrict__ A,
    const __hip_bfloat16* __restrict__ Bt,
    __hip_bfloat16* __restrict__ C, int M, int N, int Kp, int ldC)
{
    __shared__ __align__(16) short lds[2][16384];
    const int tid = threadIdx.x;
    const int w = tid >> 6, l = tid & 63;

    int nwg = gridDim.x * gridDim.y;
    int wg = blockIdx.y * gridDim.x + blockIdx.x;
    int q = nwg >> 3, r8 = nwg & 7;
    int xcd = wg & 7, lo = wg >> 3;
    int swz = (xcd < r8) ? (xcd * (q + 1) + lo) : (r8 * (q + 1) + (xcd - r8) * q + lo);
    const int bm = (swz / gridDim.x) * 128, bn = (swz % gridDim.x) * 128;

    const int wr = w >> 1, wc = w & 1;
    const int lane15 = l & 15, lhi = l >> 4;

    const __hip_bfloat16* gA = A + (size_t)bm * Kp;
    const __hip_bfloat16* gB = Bt + (size_t)bn * Kp;

    f32x4 acc[4][4] = {};

    const int nk = Kp >> 6;
    stage_tile(gA, Kp, gB, Kp, &lds[0][0], w, l);
    __syncthreads();
    int cur = 0;
    for (int t = 0; t < nk; ++t) {
        if (t + 1 < nk)
            stage_tile(gA + (t + 1) * 64, Kp, gB + (t + 1) * 64, Kp, &lds[cur ^ 1][0], w, l);
        const short* bA = &lds[cur][0];
        const short* bB = &lds[cur][8192];
#pragma unroll
        for (int ks = 0; ks < 2; ++ks) {
            bf16x8 af[4], bfr[4];
#pragma unroll
            for (int m = 0; m < 4; ++m) {
                int r = wr * 64 + m * 16 + lane15;
                int slot = (ks * 4 + lhi) ^ (r & 7);
                af[m] = *(const bf16x8*)(bA + r * 64 + slot * 8);
            }
#pragma unroll
            for (int n = 0; n < 4; ++n) {
                int r = wc * 64 + n * 16 + lane15;
                int slot = (ks * 4 + lhi) ^ (r & 7);
                bfr[n] = *(const bf16x8*)(bB + r * 64 + slot * 8);
            }
#pragma unroll
            for (int m = 0; m < 4; ++m)
#pragma unroll
                for (int n = 0; n < 4; ++n)
                    acc[m][n] = __builtin_amdgcn_mfma_f32_16x16x32_bf16(
                        af[m], bfr[n], acc[m][n], 0, 0, 0);
        }
        __syncthreads();
        cur ^= 1;
    }
#pragma unroll
    for (int m = 0; m < 4; ++m) {
#pragma unroll
        for (int n = 0; n < 4; ++n) {
            int col = bn + wc * 64 + n * 16 + lane15;
            if (col >= N) continue;
            int row0 = bm + wr * 64 + m * 16 + lhi * 4;
#pragma unroll
            for (int q2 = 0; q2 < 4; ++q2)
                C[(size_t)(row0 + q2) * ldC + col] = __float2bfloat16(acc[m][n][q2]);
        }
    }
}

// ---------------------------------------------------------------------------
// MFMA bf16 split-K GEMM (atomic-free partial slices)
// ---------------------------------------------------------------------------
__global__ __launch_bounds__(256, 2) void gemm_mfma_splitk(
    const __hip_bfloat16* __restrict__ A,
    const __hip_bfloat16* __restrict__ Bt,
    float* __restrict__ P, int M, int N, int Kp, int tps)
{
    __shared__ __align__(16) short lds[2][16384];
    const int tid = threadIdx.x;
    const int w = tid >> 6, l = tid & 63;
    const int bm = blockIdx.y * 128, bn = blockIdx.x * 128;
    const int z = blockIdx.z;
    const int wr = w >> 1, wc = w & 1;
    const int lane15 = l & 15, lhi = l >> 4;

    const __hip_bfloat16* gA = A + (size_t)bm * Kp + z * tps * 64;
    const __hip_bfloat16* gB = Bt + (size_t)bn * Kp + z * tps * 64;

    f32x4 acc[4][4] = {};

    const int nk = tps;
    stage_tile(gA, Kp, gB, Kp, &lds[0][0], w, l);
    __syncthreads();
    int cur = 0;
    for (int t = 0; t < nk; ++t) {
        if (t + 1 < nk)
            stage_tile(gA + (t + 1) * 64, Kp, gB + (t + 1) * 64, Kp, &lds[cur ^ 1][0], w, l);
        const short* bA = &lds[cur][0];
        const short* bB = &lds[cur][8192];
#pragma unroll
        for (int ks = 0; ks < 2; ++ks) {
            bf16x8 af[4], bfr[4];
#pragma unroll
            for (int m = 0; m < 4; ++m) {
                int r = wr * 64 + m * 16 + lane15;
                int slot = (ks * 4 + lhi) ^ (r & 7);
                af[m] = *(const bf16x8*)(bA + r * 64 + slot * 8);
            }
#pragma unroll
            for (int n = 0; n < 4; ++n) {
                int r = wc * 64 + n * 16 + lane15;
                int slot = (ks * 4 + lhi) ^ (r & 7);
                bfr[n] = *(const bf16x8*)(bB + r * 64 + slot * 8);
            }
#pragma unroll
            for (int m = 0; m < 4; ++m)
#pragma unroll
                for (int n = 0; n < 4; ++n)
                    acc[m][n] = __builtin_amdgcn_mfma_f32_16x16x32_bf16(
                        af[m], bfr[n], acc[m][n], 0, 0, 0);
        }
        __syncthreads();
        cur ^= 1;
    }
    float* Pz = P + (size_t)z * M * N;
#pragma unroll
    for (int m = 0; m < 4; ++m) {
#pragma unroll
        for (int n = 0; n < 4; ++n) {
            int col = bn + wc * 64 + n * 16 + lane15;
            if (col >= N) continue;
            int row0 = bm + wr * 64 + m * 16 + lhi * 4;
#pragma unroll
            for (int q2 = 0; q2 < 4; ++q2) {
                int row = row0 + q2;
                if (row < M) Pz[(size_t)row * N + col] = acc[m][n][q2];
            }
        }
    }
}

// ---------------------------------------------------------------------------
// MFMA conv GEMM (zero-im2col, NHC bf16)
// ---------------------------------------------------------------------------
template<int Ci, int Co, int Lout>
__global__ __launch_bounds__(256, 2) void gemm_conv_bf16(
    const __hip_bfloat16* __restrict__ A,
    const __hip_bfloat16* __restrict__ Bt,
    const float* __restrict__ bias,
    __hip_bfloat16* __restrict__ C)
{
    const int Kp = 8 * Ci;
    __shared__ __align__(16) short lds[2][16384];
    const int tid = threadIdx.x;
    const int w = tid >> 6, l = tid & 63;
    const int bm = blockIdx.y * 128;          // = n*128
    const int wr = w >> 1, wc = w & 1;
    const int lane15 = l & 15, lhi = l >> 4;

    const __hip_bfloat16* gA = A + (size_t)bm * Ci;
    const __hip_bfloat16* gB = Bt;

    f32x4 acc[4][4] = {};

    const int nk = Kp >> 6;
    stage_tile(gA, Ci, gB, Kp, &lds[0][0], w, l);
    __syncthreads();
    int cur = 0;
    for (int t = 0; t < nk; ++t) {
        if (t + 1 < nk)
            stage_tile(gA + (t + 1) * 64, Ci, gB + (t + 1) * 64, Kp, &lds[cur ^ 1][0], w, l);
        const short* bA = &lds[cur][0];
        const short* bB = &lds[cur][8192];
#pragma unroll
        for (int ks = 0; ks < 2; ++ks) {
            bf16x8 af[4], bfr[4];
#pragma unroll
            for (int m = 0; m < 4; ++m) {
                int r = wr * 64 + m * 16 + lane15;
                int slot = (ks * 4 + lhi) ^ (r & 7);
                af[m] = *(const bf16x8*)(bA + r * 64 + slot * 8);
            }
#pragma unroll
            for (int n = 0; n < 4; ++n) {
                int r = wc * 64 + n * 16 + lane15;
                int slot = (ks * 4 + lhi) ^ (r & 7);
                bfr[n] = *(const bf16x8*)(bB + r * 64 + slot * 8);
            }
#pragma unroll
            for (int m = 0; m < 4; ++m)
#pragma unroll
                for (int n = 0; n < 4; ++n)
                    acc[m][n] = __builtin_amdgcn_mfma_f32_16x16x32_bf16(
                        af[m], bfr[n], acc[m][n], 0, 0, 0);
        }
        __syncthreads();
        cur ^= 1;
    }
#pragma unroll
    for (int m = 0; m < 4; ++m) {
#pragma unroll
        for (int n = 0; n < 4; ++n) {
            int col = wc * 64 + n * 16 + lane15;
            if (col >= Co) continue;
            float bb = bias[col];
            int lr0 = wr * 64 + m * 16 + lhi * 4;
#pragma unroll
            for (int q2 = 0; q2 < 4; ++q2) {
                int lr = lr0 + q2;
                if (lr < Lout)
                    C[((size_t)bm + lr) * Co + col] =
                        __float2bfloat16(fmaxf(acc[m][n][q2] + bb, 0.f));
            }
        }
    }
}

// conv4 with fused maxpool(3)+flatten
__global__ __launch_bounds__(256, 2) void gemm_conv4_pool_bf16(
    const __hip_bfloat16* __restrict__ A,     // act3 NHC [n*128+t][96]
    const __hip_bfloat16* __restrict__ Bt,    // wt4 [128][768]
    const float* __restrict__ bias,
    __hip_bfloat16* __restrict__ xtb)         // [NB][4352], pads zeroed
{
    const int Ci = 96, Kp = 768;
    __shared__ __align__(16) short lds[2][16384];
    const int tid = threadIdx.x;
    const int w = tid >> 6, l = tid & 63;
    const int bm = blockIdx.y * 128;          // = n*128
    const int wr = w >> 1, wc = w & 1;
    const int lane15 = l & 15, lhi = l >> 4;

    const __hip_bfloat16* gA = A + (size_t)bm * Ci;
    const __hip_bfloat16* gB = Bt;

    f32x4 acc[4][4] = {};

    const int nk = Kp >> 6;
    stage_tile(gA, Ci, gB, Kp, &lds[0][0], w, l);
    __syncthreads();
    int cur = 0;
    for (int t = 0; t < nk; ++t) {
        if (t + 1 < nk)
            stage_tile(gA + (t + 1) * 64, Ci, gB + (t + 1) * 64, Kp, &lds[cur ^ 1][0], w, l);
        const short* bA = &lds[cur][0];
        const short* bB = &lds[cur][8192];
#pragma unroll
        for (int ks = 0; ks < 2; ++ks) {
            bf16x8 af[4], bfr[4];
#pragma unroll
            for (int m = 0; m < 4; ++m) {
                int r = wr * 64 + m * 16 + lane15;
                int slot = (ks * 4 + lhi) ^ (r & 7);
                af[m] = *(const bf16x8*)(bA + r * 64 + slot * 8);
            }
#pragma unroll
            for (int n = 0; n < 4; ++n) {
                int r = wc * 64 + n * 16 + lane15;
                int slot = (ks * 4 + lhi) ^ (r & 7);
                bfr[n] = *(const bf16x8*)(bB + r * 64 + slot * 8);
            }
#pragma unroll
            for (int m = 0; m < 4; ++m)
#pragma unroll
                for (int n = 0; n < 4; ++n)
                    acc[m][n] = __builtin_amdgcn_mfma_f32_16x16x32_bf16(
                        af[m], bfr[n], acc[m][n], 0, 0, 0);
        }
        __syncthreads();
        cur ^= 1;
    }
    float* pbuf = (float*)&lds[0][0];
#pragma unroll
    for (int m = 0; m < 4; ++m) {
#pragma unroll
        for (int n = 0; n < 4; ++n) {
            int col = wc * 64 + n * 16 + lane15;
            float bb = bias[col];
            int lr0 = wr * 64 + m * 16 + lhi * 4;
#pragma unroll
            for (int q2 = 0; q2 < 4; ++q2)
                pbuf[(lr0 + q2) * 128 + col] = acc[m][n][q2] + bb;
        }
    }
    __syncthreads();
    int nb = blockIdx.y;
    for (int idx = tid; idx < 4352; idx += 256) {
        __hip_bfloat16 v;
        if (idx >= 4224) {
            v = __float2bfloat16(0.f);
        } else {
            int c = idx / 33, tp = idx - c * 33;
            float m3 = fmaxf(fmaxf(pbuf[(tp * 3) * 128 + c], pbuf[(tp * 3 + 1) * 128 + c]),
                             pbuf[(tp * 3 + 2) * 128 + c]);
            v = __float2bfloat16(fmaxf(m3, 0.f));
        }
        xtb[(size_t)nb * 4352 + idx] = v;
    }
}

// ---------------------------------------------------------------------------
// GAT: per-node attn logits from bf16 lin — vectorized (packed bf16x2 + float2)
// Alignment: row byte base = 2*(n*Ftp + h*F); all (layer,h) are 4B-aligned.
// Weight byte base = 4*h*F; all are 8B-aligned. F is even for all layers.
// ---------------------------------------------------------------------------
__global__ void attn_ab_kernel(const __hip_bfloat16* __restrict__ lin, int Ftp,
                               const float* __restrict__ att_s,
                               const float* __restrict__ att_d,
                               float* __restrict__ a_s, float* __restrict__ a_d,
                               int H, int F)
{
    int bid = blockIdx.x;           // n*H + h
    int n = bid / H, h = bid - n * H;
    int lane = threadIdx.x;
    const unsigned short* row = (const unsigned short*)(lin + (size_t)n * Ftp + (size_t)h * F);
    const float* wsrc = att_s + (size_t)h * F;
    const float* wdst = att_d + (size_t)h * F;
    float ss = 0.f, sd = 0.f;
    int half = F >> 1;              // F even for all layers
    for (int g = lane; g < half; g += 64) {
        unsigned u = *(const unsigned*)(row + 2 * g);
        float v0 = __uint_as_float((u & 0xFFFFu) << 16);
        float v1 = __uint_as_float((u >> 16) << 16);
        float2 ws = *(const float2*)(wsrc + 2 * g);
        float2 wd = *(const float2*)(wdst + 2 * g);
        ss += v0 * ws.x + v1 * ws.y;
        sd += v0 * wd.x + v1 * wd.y;
    }
    for (int o = 32; o; o >>= 1) {
        ss += __shfl_down(ss, o);
        sd += __shfl_down(sd, o);
    }
    if (lane == 0) { a_s[bid] = ss; a_d[bid] = sd; }
}

// ---- dst-CSR build ----
__global__ void deg_kernel(const int* __restrict__ ei, int* __restrict__ deg,
                           int E, int Etot)
{
    int e = blockIdx.x * 256 + threadIdx.x;
    if (e >= Etot) return;
    int d = (e < E) ? ei[E + e] : e - E;
    atomicAdd(&deg[d], 1);
}

__global__ __launch_bounds__(256) void scan_kernel(const int* __restrict__ deg,
                                                   int* __restrict__ rowptr,
                                                   int* __restrict__ cursor, int n)
{
    __shared__ int partial[256];
    int tid = threadIdx.x;
    const int per = (n + 255) / 256;
    int base = tid * per;
    int sum = 0;
    for (int i = 0; i < per; ++i) {
        int idx = base + i;
        if (idx < n) sum += deg[idx];
    }
    partial[tid] = sum;
    __syncthreads();
    for (int offs = 1; offs < 256; offs <<= 1) {
        int v = (tid >= offs) ? partial[tid - offs] : 0;
        __syncthreads();
        partial[tid] += v;
        __syncthreads();
    }
    int run = (tid == 0) ? 0 : partial[tid - 1];
    for (int i = 0; i < per; ++i) {
        int idx = base + i;
        if (idx < n) { rowptr[idx] = run; cursor[idx] = run; run += deg[idx]; }
    }
    if (tid == 255) rowptr[n] = run;
}

__global__ void fill_csr_kernel(const int* __restrict__ ei, int* __restrict__ cursor,
                                int* __restrict__ eidx, int E, int Etot)
{
    int e = blockIdx.x * 256 + threadIdx.x;
    if (e >= Etot) return;
    int d = (e < E) ? ei[E + e] : e - E;
    int pos = atomicAdd(&cursor[d], 1);
    eidx[pos] = e;
}

// Gather with fully fused softmax (R15), 256-thread blocks (4x fewer blocks;
// per-thread code identical — threads are fully independent).
template<int ACT>
__global__ __launch_bounds__(256) void gat_gather8_kernel(
    const int* __restrict__ rowptr, const int* __restrict__ eidx,
    const int* __restrict__ ei,
    const float* __restrict__ a_s, const float* __restrict__ a_d,
    const __hip_bfloat16* __restrict__ lin, int Ftp,
    const float* __restrict__ bias,
    __hip_bfloat16* __restrict__ outh, int Kout,
    int E, int H, int F, int Ft)
{
    int d = blockIdx.x;
    int g = blockIdx.y * 256 + threadIdx.x;     // col group
    int c0 = g * 8;
    if (c0 >= Kout) return;
    bf16x8 res;
    if (c0 >= Ft) {   // pure pad group: write zeros
#pragma unroll
        for (int j = 0; j < 8; ++j) res[j] = 0;
        *(bf16x8*)(outh + (size_t)d * Kout + c0) = res;
        return;
    }
    int h0 = min(c0 / F, H - 1);
    int h1 = min((c0 + 7) / F, H - 1);
    int split = (h1 == h0) ? 8 : (F * (h0 + 1) - c0);
    float ad0 = a_d[d * H + h0];
    float ad1 = (h1 == h0) ? ad0 : a_d[d * H + h1];
    int p0 = rowptr[d], p1 = rowptr[d + 1];

    float m0 = -INFINITY, m1 = -INFINITY;
    for (int p = p0; p < p1; ++p) {
        int e = eidx[p];
        int s = (e < E) ? ei[e] : e - E;
        float v0 = a_s[s * H + h0] + ad0;
        v0 = v0 > 0.f ? v0 : 0.2f * v0;
        m0 = fmaxf(m0, v0);
        if (h1 != h0) {
            float v1 = a_s[s * H + h1] + ad1;
            v1 = v1 > 0.f ? v1 : 0.2f * v1;
            m1 = fmaxf(m1, v1);
        }
    }
    if (h1 == h0) m1 = m0;

    float acc[8] = {};
    float sum0 = 0.f, sum1 = 0.f;
    for (int p = p0; p < p1; ++p) {
        int e = eidx[p];
        int s = (e < E) ? ei[e] : e - E;
        float v0 = a_s[s * H + h0] + ad0;
        v0 = v0 > 0.f ? v0 : 0.2f * v0;
        float w0 = expf(v0 - m0);
        sum0 += w0;
        float w1;
        if (h1 != h0) {
            float v1 = a_s[s * H + h1] + ad1;
            v1 = v1 > 0.f ? v1 : 0.2f * v1;
            w1 = expf(v1 - m1);
            sum1 += w1;
        } else {
            w1 = w0;
        }
        bf16x8 v = *(const bf16x8*)(lin + (size_t)s * Ftp + c0);
#pragma unroll
        for (int j = 0; j < 8; ++j) {
            float wv = (j < split) ? w0 : w1;
            acc[j] += wv * bf16bits2float(v[j]);
        }
    }
    float rs0 = 1.f / (sum0 + 1e-16f);
    float rs1 = (h1 == h0) ? rs0 : 1.f / (sum1 + 1e-16f);

#pragma unroll
    for (int j = 0; j < 8; ++j) {
        int c = c0 + j;
        float val = 0.f;
        if (c < Ft) {
            val = acc[j] * ((j < split) ? rs0 : rs1) + bias[c];
            if (ACT == 1) val = fmaxf(val, 0.f);
            else if (ACT == 2) val = val > 0.f ? val : expm1f(val);
        }
        __hip_bfloat16 bv = __float2bfloat16(val);
        res[j] = *(const short*)&bv;
    }
    *(bf16x8*)(outh + (size_t)d * Kout + c0) = res;
}

// global max pool over bf16 h3 [N][3120] -> bf16 [NB][Kout] padded (pads zero)
__global__ void pool_max_bf16_kernel(const __hip_bfloat16* __restrict__ h,
                                     __hip_bfloat16* __restrict__ g,
                                     int B, int per, int C, int Kout)
{
    int t = blockIdx.x * blockDim.x + threadIdx.x;
    if (t >= B * Kout) return;
    int b = t / Kout, f = t - b * Kout;
    if (f >= C) { g[t] = __float2bfloat16(0.f); return; }
    const __hip_bfloat16* p = h + (size_t)b * per * C + f;
    float m = -INFINITY;
    for (int j = 0; j < per; ++j) m = fmaxf(m, __bfloat162float(p[(size_t)j * C]));
    g[t] = __float2bfloat16(m);
}

// ---------------------------------------------------------------------------
// CNN branch — conv1 vocab-factorized, split phase 1
// ---------------------------------------------------------------------------
__global__ __launch_bounds__(256) void conv1_p1_kernel(
    const int* __restrict__ target, const float* __restrict__ wt,
    float* __restrict__ Spart)
{
    __shared__ float s_S[VOCAB * 256];
    __shared__ int   s_trow[125];
    int tid = threadIdx.x;
    int n = blockIdx.x, z = blockIdx.y;
    for (int i = tid; i < VOCAB * 256; i += 256) s_S[i] = 0.f;
    if (tid < 125) s_trow[tid] = target[n * 1000 + z * 125 + tid];
    __syncthreads();
    const float* wz = wt + (size_t)(z * 125) * 256 + tid;
    for (int i = 0; i < 125; ++i) {
        int v = s_trow[i];
        s_S[v * 256 + tid] += wz[(size_t)i * 256];
    }
    __syncthreads();
    float* outp = Spart + ((size_t)n * C1SPLIT + z) * (VOCAB * 256);
    for (int i = tid; i < VOCAB * 256; i += 256) outp[i] = s_S[i];
}

__global__ __launch_bounds__(256) void conv1_p2_kernel(
    const float* __restrict__ Spart, const float* __restrict__ emb,
    const float* __restrict__ b, __hip_bfloat16* __restrict__ y)
{
    __shared__ float s_emb[VOCAB * EMB];
    __shared__ float s_S[VOCAB * 256];
    int tid = threadIdx.x;
    int n = blockIdx.x;
    for (int i = tid; i < VOCAB * EMB; i += 256) s_emb[i] = emb[i];
    const float* base = Spart + (size_t)n * C1SPLIT * (VOCAB * 256);
    for (int i = tid; i < VOCAB * 256; i += 256) {
        float s = 0.f;
#pragma unroll
        for (int z = 0; z < C1SPLIT; ++z) s += base[(size_t)z * (VOCAB * 256) + i];
        s_S[i] = s;
    }
    __syncthreads();
    for (int idx = tid; idx < 121 * 32; idx += 256) {
        int t = idx >> 5, o = idx & 31;
        float acc = b[o];
#pragma unroll
        for (int v = 0; v < VOCAB; ++v) {
            const float* Sv = s_S + v * 256 + o * 8;
            const float* ev = s_emb + v * EMB + t;
#pragma unroll
            for (int k = 0; k < 8; ++k) acc += Sv[k] * ev[k];
        }
        y[((size_t)n * LP + t) * 32 + o] = __float2bfloat16(fmaxf(acc, 0.f));
    }
}

// ---------------------------------------------------------------------------
// Host-side launch
// ---------------------------------------------------------------------------
extern "C" void kernel_launch(void* const* d_in, const int* in_sizes, int n_in,
                              void* d_out, int out_size, void* d_ws, size_t ws_size,
                              hipStream_t stream)
{
    const float* x      = (const float*)d_in[0];
    const int*   ei     = (const int*)d_in[1];
    const int*   target = (const int*)d_in[3];
    const float* W1  = (const float*)d_in[4];
    const float* as1 = (const float*)d_in[5];
    const float* ad1 = (const float*)d_in[6];
    const float* b1  = (const float*)d_in[7];
    const float* W2  = (const float*)d_in[8];
    const float* as2 = (const float*)d_in[9];
    const float* ad2 = (const float*)d_in[10];
    const float* b2  = (const float*)d_in[11];
    const float* W3  = (const float*)d_in[12];
    const float* as3 = (const float*)d_in[13];
    const float* ad3 = (const float*)d_in[14];
    const float* b3  = (const float*)d_in[15];
    const float* fc_g1_w = (const float*)d_in[16];
    const float* fc_g1_b = (const float*)d_in[17];
    const float* fc_g2_w = (const float*)d_in[18];
    const float* fc_g2_b = (const float*)d_in[19];
    const float* emb_xt  = (const float*)d_in[20];
    const float* cw1 = (const float*)d_in[21];
    const float* cb1 = (const float*)d_in[22];
    const float* cw2 = (const float*)d_in[23];
    const float* cb2 = (const float*)d_in[24];
    const float* cw3 = (const float*)d_in[25];
    const float* cb3 = (const float*)d_in[26];
    const float* cw4 = (const float*)d_in[27];
    const float* cb4 = (const float*)d_in[28];
    const float* fc1_xt_w = (const float*)d_in[29];
    const float* fc1_xt_b = (const float*)d_in[30];
    const float* fc2_xt_w = (const float*)d_in[31];
    const float* fc2_xt_b = (const float*)d_in[32];
    const float* fc1_w = (const float*)d_in[33];
    const float* fc1_b = (const float*)d_in[34];
    const float* fc2_w = (const float*)d_in[35];
    const float* fc2_b = (const float*)d_in[36];
    const float* out_w = (const float*)d_in[37];
    const float* out_b = (const float*)d_in[38];
    float* out = (float*)d_out;

    const int N = NNODES, E = NEDGES, Etot = E + N;
    const size_t MB = 1024 * 1024;

    // ---- workspace carve ----
    char* ws = (char*)d_ws;
    size_t off = 0;
    auto alloc = [&](size_t bytes) -> char* {
        char* p = ws + off;
        off = (off + bytes + 255) & ~(size_t)255;
        return p;
    };
    const size_t BIG = (size_t)N * 3120 * sizeof(float);   // 127.8 MB
    char*  bufA  = alloc(BIG);
    char*  bufB  = alloc(BIG);
    float*    a_s   = (float*)alloc((size_t)N * 10 * 4);
    float*    a_d   = (float*)alloc((size_t)N * 10 * 4);
    float*    g1    = (float*)alloc((size_t)NB * 1024 * 4);
    float*    xt1   = (float*)alloc((size_t)NB * 1024 * 4);
    __hip_bfloat16* gbufb = (__hip_bfloat16*)alloc((size_t)NB * 3200 * 2);
    __hip_bfloat16* xtb   = (__hip_bfloat16*)alloc((size_t)NB * 4352 * 2);
    int*      deg     = (int*)alloc((size_t)N * 4);
    int*      rowptr  = (int*)alloc((size_t)(N + 1) * 4);
    int*      cursor  = (int*)alloc((size_t)N * 4);
    int*      eidx    = (int*)alloc((size_t)Etot * 4);

    __hip_bfloat16* linb = (__hip_bfloat16*)bufA;
    __hip_bfloat16* Wt   = (__hip_bfloat16*)(bufA + 64 * MB);
    __hip_bfloat16* xb   = (__hip_bfloat16*)(bufA + 80 * MB);   // lin1 A, 2.6 MB
    __hip_bfloat16* hbf1 = (__hip_bfloat16*)bufB;
    __hip_bfloat16* hbf2 = (__hip_bfloat16*)(bufB + 20 * MB);
    __hip_bfloat16* hbf3 = (__hip_bfloat16*)bufB;
    __hip_bfloat16* Wt2  = (__hip_bfloat16*)(bufB + 105 * MB);
    float*          P4   = (float*)(bufB + 115 * MB);           // 12.8 MB slices

    // CNN scratch in bufA (dead after GAT layer 3)
    char* cnn = bufA;
    auto calloc2 = [&](size_t bytes) -> char* {
        char* p = cnn;
        cnn += (bytes + 255) & ~(size_t)255;
        return p;
    };
    __hip_bfloat16* act1 = (__hip_bfloat16*)calloc2((size_t)NB * LP * 32 * 2 + 4096);
    __hip_bfloat16* act2 = (__hip_bfloat16*)calloc2((size_t)NB * LP * 64 * 2 + 4096);
    __hip_bfloat16* act3 = (__hip_bfloat16*)calloc2((size_t)NB * LP * 96 * 2 + 4096);
    __hip_bfloat16* wt2  = (__hip_bfloat16*)calloc2((size_t)128 * 256 * 2);
    __hip_bfloat16* wt3  = (__hip_bfloat16*)calloc2((size_t)128 * 512 * 2);
    __hip_bfloat16* wt4  = (__hip_bfloat16*)calloc2((size_t)128 * 768 * 2);
    float* wt1f  = (float*)calloc2((size_t)1000 * 256 * 4);                 // 1.02 MB
    float* Spart = (float*)calloc2((size_t)NB * C1SPLIT * VOCAB * 256 * 4); // 54.5 MB

    // ---- build dst-CSR once ----
    {
        (void)hipMemsetAsync(deg, 0, (size_t)N * 4, stream);
        deg_kernel<<<(Etot + 255) / 256, 256, 0, stream>>>(ei, deg, E, Etot);
        scan_kernel<<<1, 256, 0, stream>>>(deg, rowptr, cursor, N);
        fill_csr_kernel<<<(Etot + 255) / 256, 256, 0, stream>>>(ei, cursor, eidx, E, Etot);
    }

    // ---- bf16 MFMA split-K head GEMM (A pre-cast bf16 [M][Kp], relu) ----
    auto head_gemm_mfma = [&](const __hip_bfloat16* Ab_, const float* W, const float* bias,
                              float* C, int M, int Nc, int K, int Kp, int S) {
        int tps = (Kp / 64) / S;
        transpose_cast_kernel<<<dim3(Kp / 32, Nc / 32), 256, 0, stream>>>(W, Wt2, K, Nc, Kp, Nc);
        dim3 g(Nc / 128, M / 128, S);
        gemm_mfma_splitk<<<g, 256, 0, stream>>>(Ab_, Wt2, P4, M, Nc, Kp, tps);
        int tot = M * Nc;
        reduce_bias_relu_ld_kernel<<<(tot + 255) / 256, 256, 0, stream>>>(P4, bias, C, M, Nc, S, Nc);
    };

    // ---- GAT attn + fused-softmax CSR-gather ----
    auto gat_tail = [&](const float* atts, const float* attd, const float* bias,
                        int H, int F, int Ftp, int act,
                        const __hip_bfloat16* lin, __hip_bfloat16* outh, int Kout) {
        attn_ab_kernel<<<N * H, 64, 0, stream>>>(lin, Ftp, atts, attd, a_s, a_d, H, F);
        int Ft = H * F;
        int groups = Kout / 8;
        dim3 gg(N, (groups + 255) / 256);
        if (act == 1)
            gat_gather8_kernel<1><<<gg, 256, 0, stream>>>(rowptr, eidx, ei, a_s, a_d, lin, Ftp, bias, outh, Kout, E, H, F, Ft);
        else
            gat_gather8_kernel<2><<<gg, 256, 0, stream>>>(rowptr, eidx, ei, a_s, a_d, lin, Ftp, bias, outh, Kout, E, H, F, Ft);
    };

    // ---- layer 1: MFMA GEMM (x cast to bf16, Kp=128) -> bf16 lin [N][784] ----
    {
        (void)hipMemsetAsync(linb, 0, (size_t)N * 784 * 2, stream);
        cast_a_kernel<<<(N * 128 + 255) / 256, 256, 0, stream>>>(x, xb, N, 78, 128);
        transpose_cast_kernel<<<dim3(4, 28), 256, 0, stream>>>(W1, Wt, 78, 780, 128, 896);
        gemm_mfma_bf16<<<dim3(7, N / 128), 256, 0, stream>>>(xb, Wt, linb, N, 780, 128, 784);
        gat_tail(as1, ad1, b1, 10, 78, 784, 2, linb, hbf1, 832);
    }
    // ---- layer 2: MFMA GEMM -> lin [N][1560] ----
    {
        const int Kp = 832, Nout = 1560, Npad = 1664;
        transpose_cast_kernel<<<dim3(Kp / 32, Npad / 32), 256, 0, stream>>>(W2, Wt, 780, Nout, Kp, Npad);
        gemm_mfma_bf16<<<dim3(Npad / 128, N / 128), 256, 0, stream>>>(hbf1, Wt, linb, N, Nout, Kp, Nout);
        gat_tail(as2, ad2, b2, 2, 780, 1560, 1, linb, hbf2, 1600);
    }
    // ---- layer 3: MFMA GEMM -> lin [N][3120] ----
    {
        const int Kp = 1600, Nout = 3120, Npad = 3200;
        transpose_cast_kernel<<<dim3(Kp / 32, Npad / 32), 256, 0, stream>>>(W3, Wt, 1560, Nout, Kp, Npad);
        gemm_mfma_bf16<<<dim3(Npad / 128, N / 128), 256, 0, stream>>>(hbf2, Wt, linb, N, Nout, Kp, Nout);
        gat_tail(as3, ad3, b3, 1, 3120, 3120, 1, linb, hbf3, 3120);
    }

    // global max pool (bf16 in, bf16 padded out) + fc_g1 (MFMA split-K)
    {
        int tot = NB * 3200;
        pool_max_bf16_kernel<<<(tot + 255) / 256, 256, 0, stream>>>(hbf3, gbufb, NB, N / NB, 3120, 3200);
        head_gemm_mfma(gbufb, fc_g1_w, fc_g1_b, g1, NB, 1024, 3120, 3200, 5);
    }

    // ---- CNN branch (bufA free now) ----
    {
        conv_wt_all_kernel<<<(64 * 32 * 8 + 96 * 64 * 8 + 128 * 96 * 8 + 32 * 8000 + 255) / 256,
                             256, 0, stream>>>(cw2, cw3, cw4, cw1, wt2, wt3, wt4, wt1f);
        conv1_p1_kernel<<<dim3(NB, C1SPLIT), 256, 0, stream>>>(target, wt1f, Spart);
        conv1_p2_kernel<<<NB, 256, 0, stream>>>(Spart, emb_xt, cb1, act1);
        gemm_conv_bf16<32, 64, 114><<<dim3(1, NB), 256, 0, stream>>>(act1, wt2, cb2, act2);
        gemm_conv_bf16<64, 96, 107><<<dim3(1, NB), 256, 0, stream>>>(act2, wt3, cb3, act3);
        gemm_conv4_pool_bf16<<<dim3(1, NB), 256, 0, stream>>>(act3, wt4, cb4, xtb);
        head_gemm_mfma(xtb, fc1_xt_w, fc1_xt_b, xt1, NB, 1024, 4224, 4352, 4);
    }

    // ---- fully fused FC head (1024 threads: 16 waves/CU) ----
    fused_head_kernel<<<NB, 1024, 0, stream>>>(
        g1, xt1, fc_g2_w, fc_g2_b, fc2_xt_w, fc2_xt_b,
        fc1_w, fc1_b, fc2_w, fc2_b, out_w, out_b, out);
}

// Round 20
// 699.771 us; speedup vs baseline: 1.0322x; 1.0322x over previous
//
#include <hip/hip_runtime.h>
#include <hip/hip_bf16.h>
#include <math.h>

// ---------------------------------------------------------------------------
// Constants (problem-fixed)
// ---------------------------------------------------------------------------
static const int NNODES = 10240;
static const int NEDGES = 40960;
static const int NB     = 256;     // graphs / batch
static const int VOCAB  = 26;
static const int EMB    = 128;
static const int LP     = 128;     // padded t-length for NHC conv activations
static const int C1SPLIT = 8;      // conv1 phase-1 i-split (1000/8 = 125)

typedef short bf16x8 __attribute__((ext_vector_type(8)));   // 8 bf16 (4 VGPRs)
typedef float f32x4  __attribute__((ext_vector_type(4)));   // 4 fp32

__device__ __forceinline__ float bf16bits2float(short s) {
    return __uint_as_float(((unsigned)(unsigned short)s) << 16);
}

// ---------------------------------------------------------------------------
// reduce S slices + bias + relu -> C (ldC)  (MFMA split-K epilogue)
// ---------------------------------------------------------------------------
__global__ void reduce_bias_relu_ld_kernel(const float* __restrict__ P,
                                           const float* __restrict__ bias,
                                           float* __restrict__ C,
                                           int M, int N, int S, int ldC)
{
    int t = blockIdx.x * 256 + threadIdx.x;
    if (t >= M * N) return;
    int r = t / N, c = t - r * N;
    float v = bias[c];
    for (int s = 0; s < S; ++s) v += P[(size_t)s * M * N + t];
    C[(size_t)r * ldC + c] = fmaxf(v, 0.f);
}

// ---------------------------------------------------------------------------
// Fully fused FC head, 1024 threads/block (16 waves/CU).
// ---------------------------------------------------------------------------
__global__ __launch_bounds__(1024) void fused_head_kernel(
    const float* __restrict__ g1, const float* __restrict__ xt1,
    const float* __restrict__ fc_g2_w, const float* __restrict__ fc_g2_b,
    const float* __restrict__ fc2_xt_w, const float* __restrict__ fc2_xt_b,
    const float* __restrict__ fc1_w, const float* __restrict__ fc1_b,
    const float* __restrict__ fc2_w, const float* __restrict__ fc2_b,
    const float* __restrict__ out_w, const float* __restrict__ out_b,
    float* __restrict__ out)
{
    __shared__ float s_in[2048];   // g1 row | xt1 row
    __shared__ float s_part[1024];
    __shared__ float s_xc[256];
    __shared__ float s_f1[1024];
    __shared__ float s_f2[256];
    __shared__ float s_red[4];
    int r = blockIdx.x, t = threadIdx.x;
    for (int i = t; i < 2048; i += 1024)
        s_in[i] = (i < 1024) ? g1[(size_t)r * 1024 + i]
                             : xt1[(size_t)r * 1024 + (i - 1024)];
    __syncthreads();
    // phase A: xc; output c = t&255, K-quarter q = t>>8
    {
        int c = t & 255, q = t >> 8;
        const float* W  = (c < 128) ? fc_g2_w : fc2_xt_w;
        const float* in = (c < 128) ? s_in : s_in + 1024;
        int cc = c & 127;
        int k0 = q * 256;
        float a0 = 0.f, a1 = 0.f, a2 = 0.f, a3 = 0.f;
#pragma unroll 4
        for (int k = 0; k < 256; k += 4) {
            a0 += in[k0 + k + 0] * W[(size_t)(k0 + k + 0) * 128 + cc];
            a1 += in[k0 + k + 1] * W[(size_t)(k0 + k + 1) * 128 + cc];
            a2 += in[k0 + k + 2] * W[(size_t)(k0 + k + 2) * 128 + cc];
            a3 += in[k0 + k + 3] * W[(size_t)(k0 + k + 3) * 128 + cc];
        }
        s_part[t] = (a0 + a1) + (a2 + a3);
    }
    __syncthreads();
    if (t < 256) {
        const float* bb = (t < 128) ? fc_g2_b : fc2_xt_b;
        s_xc[t] = bb[t & 127] + (s_part[t] + s_part[t + 256])
                              + (s_part[t + 512] + s_part[t + 768]);
    }
    __syncthreads();
    // phase B: f1 col = t, K=256
    {
        float b0 = 0.f, b1 = 0.f, b2 = 0.f, b3 = 0.f;
#pragma unroll 4
        for (int k = 0; k < 256; k += 4) {
            b0 += s_xc[k + 0] * fc1_w[(size_t)(k + 0) * 1024 + t];
            b1 += s_xc[k + 1] * fc1_w[(size_t)(k + 1) * 1024 + t];
            b2 += s_xc[k + 2] * fc1_w[(size_t)(k + 2) * 1024 + t];
            b3 += s_xc[k + 3] * fc1_w[(size_t)(k + 3) * 1024 + t];
        }
        s_f1[t] = fmaxf(fc1_b[t] + ((b0 + b1) + (b2 + b3)), 0.f);
    }
    __syncthreads();
    // phase C: f2; output c = t&255, K-quarter q = t>>8
    {
        int c = t & 255, q = t >> 8;
        int k0 = q * 256;
        float c0 = 0.f, c1 = 0.f, c2 = 0.f, c3 = 0.f;
#pragma unroll 4
        for (int k = 0; k < 256; k += 4) {
            c0 += s_f1[k0 + k + 0] * fc2_w[(size_t)(k0 + k + 0) * 256 + c];
            c1 += s_f1[k0 + k + 1] * fc2_w[(size_t)(k0 + k + 1) * 256 + c];
            c2 += s_f1[k0 + k + 2] * fc2_w[(size_t)(k0 + k + 2) * 256 + c];
            c3 += s_f1[k0 + k + 3] * fc2_w[(size_t)(k0 + k + 3) * 256 + c];
        }
        s_part[t] = (c0 + c1) + (c2 + c3);
    }
    __syncthreads();
    if (t < 256)
        s_f2[t] = fmaxf(fc2_b[t] + (s_part[t] + s_part[t + 256])
                                 + (s_part[t + 512] + s_part[t + 768]), 0.f);
    __syncthreads();
    // phase D: out (first 4 waves)
    if (t < 256) {
        float p = s_f2[t] * out_w[t];
        for (int o = 32; o; o >>= 1) p += __shfl_down(p, o);
        if ((t & 63) == 0) s_red[t >> 6] = p;
    }
    __syncthreads();
    if (t == 0)
        out[r] = s_red[0] + s_red[1] + s_red[2] + s_red[3] + out_b[0];
}

// ---------------------------------------------------------------------------
// casts
// ---------------------------------------------------------------------------
__global__ void cast_a_kernel(const float* __restrict__ in, __hip_bfloat16* __restrict__ out,
                              int M, int K, int Kp)
{
    int idx = blockIdx.x * 256 + threadIdx.x;
    if (idx >= M * Kp) return;
    int r = idx / Kp, k = idx - r * Kp;
    out[idx] = __float2bfloat16(k < K ? in[(size_t)r * K + k] : 0.f);
}

__global__ __launch_bounds__(256) void transpose_cast_kernel(
    const float* __restrict__ in, __hip_bfloat16* __restrict__ out,
    int K, int N, int Kp, int Npad)
{
    __shared__ float tile[32][33];
    int k0 = blockIdx.x * 32;
    int n0 = blockIdx.y * 32;
    int tx = threadIdx.x & 31;
    int ty = threadIdx.x >> 5;
#pragma unroll
    for (int j = 0; j < 4; ++j) {
        int k = k0 + ty + j * 8, n = n0 + tx;
        tile[ty + j * 8][tx] = (k < K && n < N) ? in[(size_t)k * N + n] : 0.f;
    }
    __syncthreads();
#pragma unroll
    for (int j = 0; j < 4; ++j) {
        int n = n0 + ty + j * 8, k = k0 + tx;
        if (n < Npad && k < Kp)
            out[(size_t)n * Kp + k] = __float2bfloat16(tile[tx][ty + j * 8]);
    }
}

// merged conv weight prep: conv2/3/4 k-major bf16 + conv1 f32 transpose
__global__ void conv_wt_all_kernel(
    const float* __restrict__ cw2, const float* __restrict__ cw3,
    const float* __restrict__ cw4, const float* __restrict__ cw1,
    __hip_bfloat16* __restrict__ wt2, __hip_bfloat16* __restrict__ wt3,
    __hip_bfloat16* __restrict__ wt4, float* __restrict__ wt1f)
{
    int idx = blockIdx.x * 256 + threadIdx.x;
    const int n2 = 64 * 32 * 8, n3 = 96 * 64 * 8, n4 = 128 * 96 * 8;
    if (idx < n2) {
        int o = idx / (32 * 8), rem = idx - o * 32 * 8;
        int i = rem >> 3, k = rem & 7;
        wt2[(size_t)o * 256 + k * 32 + i] = __float2bfloat16(cw2[idx]);
    } else if (idx < n2 + n3) {
        int j = idx - n2;
        int o = j / (64 * 8), rem = j - o * 64 * 8;
        int i = rem >> 3, k = rem & 7;
        wt3[(size_t)o * 512 + k * 64 + i] = __float2bfloat16(cw3[j]);
    } else if (idx < n2 + n3 + n4) {
        int j = idx - n2 - n3;
        int o = j / (96 * 8), rem = j - o * 96 * 8;
        int i = rem >> 3, k = rem & 7;
        wt4[(size_t)o * 768 + k * 96 + i] = __float2bfloat16(cw4[j]);
    } else {
        int j = idx - n2 - n3 - n4;
        if (j >= 32 * 8000) return;
        int o = j / 8000, rem = j - o * 8000;
        int i = rem >> 3, k = rem & 7;
        wt1f[(size_t)i * 256 + o * 8 + k] = cw1[j];
    }
}

// ---------------------------------------------------------------------------
// Shared MFMA staging
// ---------------------------------------------------------------------------
__device__ __forceinline__ void stage_tile(
    const __hip_bfloat16* __restrict__ gA, int ldA,
    const __hip_bfloat16* __restrict__ gB, int ldB,
    short* ldsbuf, int w, int l)
{
#pragma unroll
    for (int j = 0; j < 4; ++j) {
        int u = (w * 4 + j) * 64 + l;
        int r = u >> 3, s = u & 7;
        const __hip_bfloat16* src = gA + (size_t)r * ldA + ((s ^ (r & 7)) << 3);
        __builtin_amdgcn_global_load_lds(
            (const __attribute__((address_space(1))) void*)src,
            (__attribute__((address_space(3))) void*)(ldsbuf + (w * 4 + j) * 512),
            16, 0, 0);
    }
#pragma unroll
    for (int j = 0; j < 4; ++j) {
        int u = (w * 4 + j) * 64 + l;
        int r = u >> 3, s = u & 7;
        const __hip_bfloat16* src = gB + (size_t)r * ldB + ((s ^ (r & 7)) << 3);
        __builtin_amdgcn_global_load_lds(
            (const __attribute__((address_space(1))) void*)src,
            (__attribute__((address_space(3))) void*)(ldsbuf + 8192 + (w * 4 + j) * 512),
            16, 0, 0);
    }
}

// ---------------------------------------------------------------------------
// MFMA bf16 GEMM (FC form), bf16 output, XCD-bijective block swizzle (m204).
// ---------------------------------------------------------------------------
__global__ __launch_bounds__(256, 2) void gemm_mfma_bf16(
    const __hip_bfloat16* __restrict__ A,
    const __hip_bfloat16* __restrict__ Bt,
    __hip_bfloat16* __restrict__ C, int M, int N, int Kp, int ldC)
{
    __shared__ __align__(16) short lds[2][16384];
    const int tid = threadIdx.x;
    const int w = tid >> 6, l = tid & 63;

    int nwg = gridDim.x * gridDim.y;
    int wg = blockIdx.y * gridDim.x + blockIdx.x;
    int q = nwg >> 3, r8 = nwg & 7;
    int xcd = wg & 7, lo = wg >> 3;
    int swz = (xcd < r8) ? (xcd * (q + 1) + lo) : (r8 * (q + 1) + (xcd - r8) * q + lo);
    const int bm = (swz / gridDim.x) * 128, bn = (swz % gridDim.x) * 128;

    const int wr = w >> 1, wc = w & 1;
    const int lane15 = l & 15, lhi = l >> 4;

    const __hip_bfloat16* gA = A + (size_t)bm * Kp;
    const __hip_bfloat16* gB = Bt + (size_t)bn * Kp;

    f32x4 acc[4][4] = {};

    const int nk = Kp >> 6;
    stage_tile(gA, Kp, gB, Kp, &lds[0][0], w, l);
    __syncthreads();
    int cur = 0;
    for (int t = 0; t < nk; ++t) {
        if (t + 1 < nk)
            stage_tile(gA + (t + 1) * 64, Kp, gB + (t + 1) * 64, Kp, &lds[cur ^ 1][0], w, l);
        const short* bA = &lds[cur][0];
        const short* bB = &lds[cur][8192];
#pragma unroll
        for (int ks = 0; ks < 2; ++ks) {
            bf16x8 af[4], bfr[4];
#pragma unroll
            for (int m = 0; m < 4; ++m) {
                int r = wr * 64 + m * 16 + lane15;
                int slot = (ks * 4 + lhi) ^ (r & 7);
                af[m] = *(const bf16x8*)(bA + r * 64 + slot * 8);
            }
#pragma unroll
            for (int n = 0; n < 4; ++n) {
                int r = wc * 64 + n * 16 + lane15;
                int slot = (ks * 4 + lhi) ^ (r & 7);
                bfr[n] = *(const bf16x8*)(bB + r * 64 + slot * 8);
            }
#pragma unroll
            for (int m = 0; m < 4; ++m)
#pragma unroll
                for (int n = 0; n < 4; ++n)
                    acc[m][n] = __builtin_amdgcn_mfma_f32_16x16x32_bf16(
                        af[m], bfr[n], acc[m][n], 0, 0, 0);
        }
        __syncthreads();
        cur ^= 1;
    }
#pragma unroll
    for (int m = 0; m < 4; ++m) {
#pragma unroll
        for (int n = 0; n < 4; ++n) {
            int col = bn + wc * 64 + n * 16 + lane15;
            if (col >= N) continue;
            int row0 = bm + wr * 64 + m * 16 + lhi * 4;
#pragma unroll
            for (int q2 = 0; q2 < 4; ++q2)
                C[(size_t)(row0 + q2) * ldC + col] = __float2bfloat16(acc[m][n][q2]);
        }
    }
}

// ---------------------------------------------------------------------------
// MFMA bf16 split-K GEMM (atomic-free partial slices)
// ---------------------------------------------------------------------------
__global__ __launch_bounds__(256, 2) void gemm_mfma_splitk(
    const __hip_bfloat16* __restrict__ A,
    const __hip_bfloat16* __restrict__ Bt,
    float* __restrict__ P, int M, int N, int Kp, int tps)
{
    __shared__ __align__(16) short lds[2][16384];
    const int tid = threadIdx.x;
    const int w = tid >> 6, l = tid & 63;
    const int bm = blockIdx.y * 128, bn = blockIdx.x * 128;
    const int z = blockIdx.z;
    const int wr = w >> 1, wc = w & 1;
    const int lane15 = l & 15, lhi = l >> 4;

    const __hip_bfloat16* gA = A + (size_t)bm * Kp + z * tps * 64;
    const __hip_bfloat16* gB = Bt + (size_t)bn * Kp + z * tps * 64;

    f32x4 acc[4][4] = {};

    const int nk = tps;
    stage_tile(gA, Kp, gB, Kp, &lds[0][0], w, l);
    __syncthreads();
    int cur = 0;
    for (int t = 0; t < nk; ++t) {
        if (t + 1 < nk)
            stage_tile(gA + (t + 1) * 64, Kp, gB + (t + 1) * 64, Kp, &lds[cur ^ 1][0], w, l);
        const short* bA = &lds[cur][0];
        const short* bB = &lds[cur][8192];
#pragma unroll
        for (int ks = 0; ks < 2; ++ks) {
            bf16x8 af[4], bfr[4];
#pragma unroll
            for (int m = 0; m < 4; ++m) {
                int r = wr * 64 + m * 16 + lane15;
                int slot = (ks * 4 + lhi) ^ (r & 7);
                af[m] = *(const bf16x8*)(bA + r * 64 + slot * 8);
            }
#pragma unroll
            for (int n = 0; n < 4; ++n) {
                int r = wc * 64 + n * 16 + lane15;
                int slot = (ks * 4 + lhi) ^ (r & 7);
                bfr[n] = *(const bf16x8*)(bB + r * 64 + slot * 8);
            }
#pragma unroll
            for (int m = 0; m < 4; ++m)
#pragma unroll
                for (int n = 0; n < 4; ++n)
                    acc[m][n] = __builtin_amdgcn_mfma_f32_16x16x32_bf16(
                        af[m], bfr[n], acc[m][n], 0, 0, 0);
        }
        __syncthreads();
        cur ^= 1;
    }
    float* Pz = P + (size_t)z * M * N;
#pragma unroll
    for (int m = 0; m < 4; ++m) {
#pragma unroll
        for (int n = 0; n < 4; ++n) {
            int col = bn + wc * 64 + n * 16 + lane15;
            if (col >= N) continue;
            int row0 = bm + wr * 64 + m * 16 + lhi * 4;
#pragma unroll
            for (int q2 = 0; q2 < 4; ++q2) {
                int row = row0 + q2;
                if (row < M) Pz[(size_t)row * N + col] = acc[m][n][q2];
            }
        }
    }
}

// ---------------------------------------------------------------------------
// MFMA conv GEMM (zero-im2col, NHC bf16)
// ---------------------------------------------------------------------------
template<int Ci, int Co, int Lout>
__global__ __launch_bounds__(256, 2) void gemm_conv_bf16(
    const __hip_bfloat16* __restrict__ A,
    const __hip_bfloat16* __restrict__ Bt,
    const float* __restrict__ bias,
    __hip_bfloat16* __restrict__ C)
{
    const int Kp = 8 * Ci;
    __shared__ __align__(16) short lds[2][16384];
    const int tid = threadIdx.x;
    const int w = tid >> 6, l = tid & 63;
    const int bm = blockIdx.y * 128;          // = n*128
    const int wr = w >> 1, wc = w & 1;
    const int lane15 = l & 15, lhi = l >> 4;

    const __hip_bfloat16* gA = A + (size_t)bm * Ci;
    const __hip_bfloat16* gB = Bt;

    f32x4 acc[4][4] = {};

    const int nk = Kp >> 6;
    stage_tile(gA, Ci, gB, Kp, &lds[0][0], w, l);
    __syncthreads();
    int cur = 0;
    for (int t = 0; t < nk; ++t) {
        if (t + 1 < nk)
            stage_tile(gA + (t + 1) * 64, Ci, gB + (t + 1) * 64, Kp, &lds[cur ^ 1][0], w, l);
        const short* bA = &lds[cur][0];
        const short* bB = &lds[cur][8192];
#pragma unroll
        for (int ks = 0; ks < 2; ++ks) {
            bf16x8 af[4], bfr[4];
#pragma unroll
            for (int m = 0; m < 4; ++m) {
                int r = wr * 64 + m * 16 + lane15;
                int slot = (ks * 4 + lhi) ^ (r & 7);
                af[m] = *(const bf16x8*)(bA + r * 64 + slot * 8);
            }
#pragma unroll
            for (int n = 0; n < 4; ++n) {
                int r = wc * 64 + n * 16 + lane15;
                int slot = (ks * 4 + lhi) ^ (r & 7);
                bfr[n] = *(const bf16x8*)(bB + r * 64 + slot * 8);
            }
#pragma unroll
            for (int m = 0; m < 4; ++m)
#pragma unroll
                for (int n = 0; n < 4; ++n)
                    acc[m][n] = __builtin_amdgcn_mfma_f32_16x16x32_bf16(
                        af[m], bfr[n], acc[m][n], 0, 0, 0);
        }
        __syncthreads();
        cur ^= 1;
    }
#pragma unroll
    for (int m = 0; m < 4; ++m) {
#pragma unroll
        for (int n = 0; n < 4; ++n) {
            int col = wc * 64 + n * 16 + lane15;
            if (col >= Co) continue;
            float bb = bias[col];
            int lr0 = wr * 64 + m * 16 + lhi * 4;
#pragma unroll
            for (int q2 = 0; q2 < 4; ++q2) {
                int lr = lr0 + q2;
                if (lr < Lout)
                    C[((size_t)bm + lr) * Co + col] =
                        __float2bfloat16(fmaxf(acc[m][n][q2] + bb, 0.f));
            }
        }
    }
}

// conv4 with fused maxpool(3)+flatten
__global__ __launch_bounds__(256, 2) void gemm_conv4_pool_bf16(
    const __hip_bfloat16* __restrict__ A,     // act3 NHC [n*128+t][96]
    const __hip_bfloat16* __restrict__ Bt,    // wt4 [128][768]
    const float* __restrict__ bias,
    __hip_bfloat16* __restrict__ xtb)         // [NB][4352], pads zeroed
{
    const int Ci = 96, Kp = 768;
    __shared__ __align__(16) short lds[2][16384];
    const int tid = threadIdx.x;
    const int w = tid >> 6, l = tid & 63;
    const int bm = blockIdx.y * 128;          // = n*128
    const int wr = w >> 1, wc = w & 1;
    const int lane15 = l & 15, lhi = l >> 4;

    const __hip_bfloat16* gA = A + (size_t)bm * Ci;
    const __hip_bfloat16* gB = Bt;

    f32x4 acc[4][4] = {};

    const int nk = Kp >> 6;
    stage_tile(gA, Ci, gB, Kp, &lds[0][0], w, l);
    __syncthreads();
    int cur = 0;
    for (int t = 0; t < nk; ++t) {
        if (t + 1 < nk)
            stage_tile(gA + (t + 1) * 64, Ci, gB + (t + 1) * 64, Kp, &lds[cur ^ 1][0], w, l);
        const short* bA = &lds[cur][0];
        const short* bB = &lds[cur][8192];
#pragma unroll
        for (int ks = 0; ks < 2; ++ks) {
            bf16x8 af[4], bfr[4];
#pragma unroll
            for (int m = 0; m < 4; ++m) {
                int r = wr * 64 + m * 16 + lane15;
                int slot = (ks * 4 + lhi) ^ (r & 7);
                af[m] = *(const bf16x8*)(bA + r * 64 + slot * 8);
            }
#pragma unroll
            for (int n = 0; n < 4; ++n) {
                int r = wc * 64 + n * 16 + lane15;
                int slot = (ks * 4 + lhi) ^ (r & 7);
                bfr[n] = *(const bf16x8*)(bB + r * 64 + slot * 8);
            }
#pragma unroll
            for (int m = 0; m < 4; ++m)
#pragma unroll
                for (int n = 0; n < 4; ++n)
                    acc[m][n] = __builtin_amdgcn_mfma_f32_16x16x32_bf16(
                        af[m], bfr[n], acc[m][n], 0, 0, 0);
        }
        __syncthreads();
        cur ^= 1;
    }
    float* pbuf = (float*)&lds[0][0];
#pragma unroll
    for (int m = 0; m < 4; ++m) {
#pragma unroll
        for (int n = 0; n < 4; ++n) {
            int col = wc * 64 + n * 16 + lane15;
            float bb = bias[col];
            int lr0 = wr * 64 + m * 16 + lhi * 4;
#pragma unroll
            for (int q2 = 0; q2 < 4; ++q2)
                pbuf[(lr0 + q2) * 128 + col] = acc[m][n][q2] + bb;
        }
    }
    __syncthreads();
    int nb = blockIdx.y;
    for (int idx = tid; idx < 4352; idx += 256) {
        __hip_bfloat16 v;
        if (idx >= 4224) {
            v = __float2bfloat16(0.f);
        } else {
            int c = idx / 33, tp = idx - c * 33;
            float m3 = fmaxf(fmaxf(pbuf[(tp * 3) * 128 + c], pbuf[(tp * 3 + 1) * 128 + c]),
                             pbuf[(tp * 3 + 2) * 128 + c]);
            v = __float2bfloat16(fmaxf(m3, 0.f));
        }
        xtb[(size_t)nb * 4352 + idx] = v;
    }
}

// ---------------------------------------------------------------------------
// GAT: per-node attn logits from bf16 lin — vectorized (packed bf16x2 + float2)
// Alignment: row byte base = 2*(n*Ftp + h*F); all (layer,h) are 4B-aligned.
// Weight byte base = 4*h*F; 8B-aligned. F is even for all layers.
// ---------------------------------------------------------------------------
__global__ void attn_ab_kernel(const __hip_bfloat16* __restrict__ lin, int Ftp,
                               const float* __restrict__ att_s,
                               const float* __restrict__ att_d,
                               float* __restrict__ a_s, float* __restrict__ a_d,
                               int H, int F)
{
    int bid = blockIdx.x;           // n*H + h
    int n = bid / H, h = bid - n * H;
    int lane = threadIdx.x;
    const unsigned short* row = (const unsigned short*)(lin + (size_t)n * Ftp + (size_t)h * F);
    const float* wsrc = att_s + (size_t)h * F;
    const float* wdst = att_d + (size_t)h * F;
    float ss = 0.f, sd = 0.f;
    int half = F >> 1;              // F even for all layers
    for (int g = lane; g < half; g += 64) {
        unsigned u = *(const unsigned*)(row + 2 * g);
        float v0 = __uint_as_float((u & 0xFFFFu) << 16);
        float v1 = __uint_as_float((u >> 16) << 16);
        float2 ws = *(const float2*)(wsrc + 2 * g);
        float2 wd = *(const float2*)(wdst + 2 * g);
        ss += v0 * ws.x + v1 * ws.y;
        sd += v0 * wd.x + v1 * wd.y;
    }
    for (int o = 32; o; o >>= 1) {
        ss += __shfl_down(ss, o);
        sd += __shfl_down(sd, o);
    }
    if (lane == 0) { a_s[bid] = ss; a_d[bid] = sd; }
}

// ---- dst-CSR build ----
__global__ void deg_kernel(const int* __restrict__ ei, int* __restrict__ deg,
                           int E, int Etot)
{
    int e = blockIdx.x * 256 + threadIdx.x;
    if (e >= Etot) return;
    int d = (e < E) ? ei[E + e] : e - E;
    atomicAdd(&deg[d], 1);
}

__global__ __launch_bounds__(256) void scan_kernel(const int* __restrict__ deg,
                                                   int* __restrict__ rowptr,
                                                   int* __restrict__ cursor, int n)
{
    __shared__ int partial[256];
    int tid = threadIdx.x;
    const int per = (n + 255) / 256;
    int base = tid * per;
    int sum = 0;
    for (int i = 0; i < per; ++i) {
        int idx = base + i;
        if (idx < n) sum += deg[idx];
    }
    partial[tid] = sum;
    __syncthreads();
    for (int offs = 1; offs < 256; offs <<= 1) {
        int v = (tid >= offs) ? partial[tid - offs] : 0;
        __syncthreads();
        partial[tid] += v;
        __syncthreads();
    }
    int run = (tid == 0) ? 0 : partial[tid - 1];
    for (int i = 0; i < per; ++i) {
        int idx = base + i;
        if (idx < n) { rowptr[idx] = run; cursor[idx] = run; run += deg[idx]; }
    }
    if (tid == 255) rowptr[n] = run;
}

__global__ void fill_csr_kernel(const int* __restrict__ ei, int* __restrict__ cursor,
                                int* __restrict__ eidx, int E, int Etot)
{
    int e = blockIdx.x * 256 + threadIdx.x;
    if (e >= Etot) return;
    int d = (e < E) ? ei[E + e] : e - E;
    int pos = atomicAdd(&cursor[d], 1);
    eidx[pos] = e;
}

// Gather with fully fused softmax (R15), 64-thread blocks (R18-verified).
template<int ACT>
__global__ __launch_bounds__(64) void gat_gather8_kernel(
    const int* __restrict__ rowptr, const int* __restrict__ eidx,
    const int* __restrict__ ei,
    const float* __restrict__ a_s, const float* __restrict__ a_d,
    const __hip_bfloat16* __restrict__ lin, int Ftp,
    const float* __restrict__ bias,
    __hip_bfloat16* __restrict__ outh, int Kout,
    int E, int H, int F, int Ft)
{
    int d = blockIdx.x;
    int g = blockIdx.y * 64 + threadIdx.x;      // col group
    int c0 = g * 8;
    if (c0 >= Kout) return;
    bf16x8 res;
    if (c0 >= Ft) {   // pure pad group: write zeros
#pragma unroll
        for (int j = 0; j < 8; ++j) res[j] = 0;
        *(bf16x8*)(outh + (size_t)d * Kout + c0) = res;
        return;
    }
    int h0 = min(c0 / F, H - 1);
    int h1 = min((c0 + 7) / F, H - 1);
    int split = (h1 == h0) ? 8 : (F * (h0 + 1) - c0);
    float ad0 = a_d[d * H + h0];
    float ad1 = (h1 == h0) ? ad0 : a_d[d * H + h1];
    int p0 = rowptr[d], p1 = rowptr[d + 1];

    float m0 = -INFINITY, m1 = -INFINITY;
    for (int p = p0; p < p1; ++p) {
        int e = eidx[p];
        int s = (e < E) ? ei[e] : e - E;
        float v0 = a_s[s * H + h0] + ad0;
        v0 = v0 > 0.f ? v0 : 0.2f * v0;
        m0 = fmaxf(m0, v0);
        if (h1 != h0) {
            float v1 = a_s[s * H + h1] + ad1;
            v1 = v1 > 0.f ? v1 : 0.2f * v1;
            m1 = fmaxf(m1, v1);
        }
    }
    if (h1 == h0) m1 = m0;

    float acc[8] = {};
    float sum0 = 0.f, sum1 = 0.f;
    for (int p = p0; p < p1; ++p) {
        int e = eidx[p];
        int s = (e < E) ? ei[e] : e - E;
        float v0 = a_s[s * H + h0] + ad0;
        v0 = v0 > 0.f ? v0 : 0.2f * v0;
        float w0 = expf(v0 - m0);
        sum0 += w0;
        float w1;
        if (h1 != h0) {
            float v1 = a_s[s * H + h1] + ad1;
            v1 = v1 > 0.f ? v1 : 0.2f * v1;
            w1 = expf(v1 - m1);
            sum1 += w1;
        } else {
            w1 = w0;
        }
        bf16x8 v = *(const bf16x8*)(lin + (size_t)s * Ftp + c0);
#pragma unroll
        for (int j = 0; j < 8; ++j) {
            float wv = (j < split) ? w0 : w1;
            acc[j] += wv * bf16bits2float(v[j]);
        }
    }
    float rs0 = 1.f / (sum0 + 1e-16f);
    float rs1 = (h1 == h0) ? rs0 : 1.f / (sum1 + 1e-16f);

#pragma unroll
    for (int j = 0; j < 8; ++j) {
        int c = c0 + j;
        float val = 0.f;
        if (c < Ft) {
            val = acc[j] * ((j < split) ? rs0 : rs1) + bias[c];
            if (ACT == 1) val = fmaxf(val, 0.f);
            else if (ACT == 2) val = val > 0.f ? val : expm1f(val);
        }
        __hip_bfloat16 bv = __float2bfloat16(val);
        res[j] = *(const short*)&bv;
    }
    *(bf16x8*)(outh + (size_t)d * Kout + c0) = res;
}

// global max pool over bf16 h3 [N][3120] -> bf16 [NB][Kout] padded (pads zero)
__global__ void pool_max_bf16_kernel(const __hip_bfloat16* __restrict__ h,
                                     __hip_bfloat16* __restrict__ g,
                                     int B, int per, int C, int Kout)
{
    int t = blockIdx.x * blockDim.x + threadIdx.x;
    if (t >= B * Kout) return;
    int b = t / Kout, f = t - b * Kout;
    if (f >= C) { g[t] = __float2bfloat16(0.f); return; }
    const __hip_bfloat16* p = h + (size_t)b * per * C + f;
    float m = -INFINITY;
    for (int j = 0; j < per; ++j) m = fmaxf(m, __bfloat162float(p[(size_t)j * C]));
    g[t] = __float2bfloat16(m);
}

// ---------------------------------------------------------------------------
// CNN branch — conv1 vocab-factorized, split phase 1
// ---------------------------------------------------------------------------
__global__ __launch_bounds__(256) void conv1_p1_kernel(
    const int* __restrict__ target, const float* __restrict__ wt,
    float* __restrict__ Spart)
{
    __shared__ float s_S[VOCAB * 256];
    __shared__ int   s_trow[125];
    int tid = threadIdx.x;
    int n = blockIdx.x, z = blockIdx.y;
    for (int i = tid; i < VOCAB * 256; i += 256) s_S[i] = 0.f;
    if (tid < 125) s_trow[tid] = target[n * 1000 + z * 125 + tid];
    __syncthreads();
    const float* wz = wt + (size_t)(z * 125) * 256 + tid;
    for (int i = 0; i < 125; ++i) {
        int v = s_trow[i];
        s_S[v * 256 + tid] += wz[(size_t)i * 256];
    }
    __syncthreads();
    float* outp = Spart + ((size_t)n * C1SPLIT + z) * (VOCAB * 256);
    for (int i = tid; i < VOCAB * 256; i += 256) outp[i] = s_S[i];
}

__global__ __launch_bounds__(256) void conv1_p2_kernel(
    const float* __restrict__ Spart, const float* __restrict__ emb,
    const float* __restrict__ b, __hip_bfloat16* __restrict__ y)
{
    __shared__ float s_emb[VOCAB * EMB];
    __shared__ float s_S[VOCAB * 256];
    int tid = threadIdx.x;
    int n = blockIdx.x;
    for (int i = tid; i < VOCAB * EMB; i += 256) s_emb[i] = emb[i];
    const float* base = Spart + (size_t)n * C1SPLIT * (VOCAB * 256);
    for (int i = tid; i < VOCAB * 256; i += 256) {
        float s = 0.f;
#pragma unroll
        for (int z = 0; z < C1SPLIT; ++z) s += base[(size_t)z * (VOCAB * 256) + i];
        s_S[i] = s;
    }
    __syncthreads();
    for (int idx = tid; idx < 121 * 32; idx += 256) {
        int t = idx >> 5, o = idx & 31;
        float acc = b[o];
#pragma unroll
        for (int v = 0; v < VOCAB; ++v) {
            const float* Sv = s_S + v * 256 + o * 8;
            const float* ev = s_emb + v * EMB + t;
#pragma unroll
            for (int k = 0; k < 8; ++k) acc += Sv[k] * ev[k];
        }
        y[((size_t)n * LP + t) * 32 + o] = __float2bfloat16(fmaxf(acc, 0.f));
    }
}

// ---------------------------------------------------------------------------
// Host-side launch
// ---------------------------------------------------------------------------
extern "C" void kernel_launch(void* const* d_in, const int* in_sizes, int n_in,
                              void* d_out, int out_size, void* d_ws, size_t ws_size,
                              hipStream_t stream)
{
    const float* x      = (const float*)d_in[0];
    const int*   ei     = (const int*)d_in[1];
    const int*   target = (const int*)d_in[3];
    const float* W1  = (const float*)d_in[4];
    const float* as1 = (const float*)d_in[5];
    const float* ad1 = (const float*)d_in[6];
    const float* b1  = (const float*)d_in[7];
    const float* W2  = (const float*)d_in[8];
    const float* as2 = (const float*)d_in[9];
    const float* ad2 = (const float*)d_in[10];
    const float* b2  = (const float*)d_in[11];
    const float* W3  = (const float*)d_in[12];
    const float* as3 = (const float*)d_in[13];
    const float* ad3 = (const float*)d_in[14];
    const float* b3  = (const float*)d_in[15];
    const float* fc_g1_w = (const float*)d_in[16];
    const float* fc_g1_b = (const float*)d_in[17];
    const float* fc_g2_w = (const float*)d_in[18];
    const float* fc_g2_b = (const float*)d_in[19];
    const float* emb_xt  = (const float*)d_in[20];
    const float* cw1 = (const float*)d_in[21];
    const float* cb1 = (const float*)d_in[22];
    const float* cw2 = (const float*)d_in[23];
    const float* cb2 = (const float*)d_in[24];
    const float* cw3 = (const float*)d_in[25];
    const float* cb3 = (const float*)d_in[26];
    const float* cw4 = (const float*)d_in[27];
    const float* cb4 = (const float*)d_in[28];
    const float* fc1_xt_w = (const float*)d_in[29];
    const float* fc1_xt_b = (const float*)d_in[30];
    const float* fc2_xt_w = (const float*)d_in[31];
    const float* fc2_xt_b = (const float*)d_in[32];
    const float* fc1_w = (const float*)d_in[33];
    const float* fc1_b = (const float*)d_in[34];
    const float* fc2_w = (const float*)d_in[35];
    const float* fc2_b = (const float*)d_in[36];
    const float* out_w = (const float*)d_in[37];
    const float* out_b = (const float*)d_in[38];
    float* out = (float*)d_out;

    const int N = NNODES, E = NEDGES, Etot = E + N;
    const size_t MB = 1024 * 1024;

    // ---- workspace carve ----
    char* ws = (char*)d_ws;
    size_t off = 0;
    auto alloc = [&](size_t bytes) -> char* {
        char* p = ws + off;
        off = (off + bytes + 255) & ~(size_t)255;
        return p;
    };
    const size_t BIG = (size_t)N * 3120 * sizeof(float);   // 127.8 MB
    char*  bufA  = alloc(BIG);
    char*  bufB  = alloc(BIG);
    float*    a_s   = (float*)alloc((size_t)N * 10 * 4);
    float*    a_d   = (float*)alloc((size_t)N * 10 * 4);
    float*    g1    = (float*)alloc((size_t)NB * 1024 * 4);
    float*    xt1   = (float*)alloc((size_t)NB * 1024 * 4);
    __hip_bfloat16* gbufb = (__hip_bfloat16*)alloc((size_t)NB * 3200 * 2);
    __hip_bfloat16* xtb   = (__hip_bfloat16*)alloc((size_t)NB * 4352 * 2);
    int*      deg     = (int*)alloc((size_t)N * 4);
    int*      rowptr  = (int*)alloc((size_t)(N + 1) * 4);
    int*      cursor  = (int*)alloc((size_t)N * 4);
    int*      eidx    = (int*)alloc((size_t)Etot * 4);

    __hip_bfloat16* linb = (__hip_bfloat16*)bufA;
    __hip_bfloat16* Wt   = (__hip_bfloat16*)(bufA + 64 * MB);
    __hip_bfloat16* xb   = (__hip_bfloat16*)(bufA + 80 * MB);   // lin1 A, 2.6 MB
    __hip_bfloat16* hbf1 = (__hip_bfloat16*)bufB;
    __hip_bfloat16* hbf2 = (__hip_bfloat16*)(bufB + 20 * MB);
    __hip_bfloat16* hbf3 = (__hip_bfloat16*)bufB;
    __hip_bfloat16* Wt2  = (__hip_bfloat16*)(bufB + 105 * MB);
    float*          P4   = (float*)(bufB + 115 * MB);           // 12.8 MB slices

    // CNN scratch in bufA (dead after GAT layer 3)
    char* cnn = bufA;
    auto calloc2 = [&](size_t bytes) -> char* {
        char* p = cnn;
        cnn += (bytes + 255) & ~(size_t)255;
        return p;
    };
    __hip_bfloat16* act1 = (__hip_bfloat16*)calloc2((size_t)NB * LP * 32 * 2 + 4096);
    __hip_bfloat16* act2 = (__hip_bfloat16*)calloc2((size_t)NB * LP * 64 * 2 + 4096);
    __hip_bfloat16* act3 = (__hip_bfloat16*)calloc2((size_t)NB * LP * 96 * 2 + 4096);
    __hip_bfloat16* wt2  = (__hip_bfloat16*)calloc2((size_t)128 * 256 * 2);
    __hip_bfloat16* wt3  = (__hip_bfloat16*)calloc2((size_t)128 * 512 * 2);
    __hip_bfloat16* wt4  = (__hip_bfloat16*)calloc2((size_t)128 * 768 * 2);
    float* wt1f  = (float*)calloc2((size_t)1000 * 256 * 4);                 // 1.02 MB
    float* Spart = (float*)calloc2((size_t)NB * C1SPLIT * VOCAB * 256 * 4); // 54.5 MB

    // ---- build dst-CSR once ----
    {
        (void)hipMemsetAsync(deg, 0, (size_t)N * 4, stream);
        deg_kernel<<<(Etot + 255) / 256, 256, 0, stream>>>(ei, deg, E, Etot);
        scan_kernel<<<1, 256, 0, stream>>>(deg, rowptr, cursor, N);
        fill_csr_kernel<<<(Etot + 255) / 256, 256, 0, stream>>>(ei, cursor, eidx, E, Etot);
    }

    // ---- bf16 MFMA split-K head GEMM (A pre-cast bf16 [M][Kp], relu) ----
    auto head_gemm_mfma = [&](const __hip_bfloat16* Ab_, const float* W, const float* bias,
                              float* C, int M, int Nc, int K, int Kp, int S) {
        int tps = (Kp / 64) / S;
        transpose_cast_kernel<<<dim3(Kp / 32, Nc / 32), 256, 0, stream>>>(W, Wt2, K, Nc, Kp, Nc);
        dim3 g(Nc / 128, M / 128, S);
        gemm_mfma_splitk<<<g, 256, 0, stream>>>(Ab_, Wt2, P4, M, Nc, Kp, tps);
        int tot = M * Nc;
        reduce_bias_relu_ld_kernel<<<(tot + 255) / 256, 256, 0, stream>>>(P4, bias, C, M, Nc, S, Nc);
    };

    // ---- GAT attn + fused-softmax CSR-gather ----
    auto gat_tail = [&](const float* atts, const float* attd, const float* bias,
                        int H, int F, int Ftp, int act,
                        const __hip_bfloat16* lin, __hip_bfloat16* outh, int Kout) {
        attn_ab_kernel<<<N * H, 64, 0, stream>>>(lin, Ftp, atts, attd, a_s, a_d, H, F);
        int Ft = H * F;
        int groups = Kout / 8;
        dim3 gg(N, (groups + 63) / 64);
        if (act == 1)
            gat_gather8_kernel<1><<<gg, 64, 0, stream>>>(rowptr, eidx, ei, a_s, a_d, lin, Ftp, bias, outh, Kout, E, H, F, Ft);
        else
            gat_gather8_kernel<2><<<gg, 64, 0, stream>>>(rowptr, eidx, ei, a_s, a_d, lin, Ftp, bias, outh, Kout, E, H, F, Ft);
    };

    // ---- layer 1: MFMA GEMM (x cast to bf16, Kp=128) -> bf16 lin [N][784] ----
    {
        (void)hipMemsetAsync(linb, 0, (size_t)N * 784 * 2, stream);
        cast_a_kernel<<<(N * 128 + 255) / 256, 256, 0, stream>>>(x, xb, N, 78, 128);
        transpose_cast_kernel<<<dim3(4, 28), 256, 0, stream>>>(W1, Wt, 78, 780, 128, 896);
        gemm_mfma_bf16<<<dim3(7, N / 128), 256, 0, stream>>>(xb, Wt, linb, N, 780, 128, 784);
        gat_tail(as1, ad1, b1, 10, 78, 784, 2, linb, hbf1, 832);
    }
    // ---- layer 2: MFMA GEMM -> lin [N][1560] ----
    {
        const int Kp = 832, Nout = 1560, Npad = 1664;
        transpose_cast_kernel<<<dim3(Kp / 32, Npad / 32), 256, 0, stream>>>(W2, Wt, 780, Nout, Kp, Npad);
        gemm_mfma_bf16<<<dim3(Npad / 128, N / 128), 256, 0, stream>>>(hbf1, Wt, linb, N, Nout, Kp, Nout);
        gat_tail(as2, ad2, b2, 2, 780, 1560, 1, linb, hbf2, 1600);
    }
    // ---- layer 3: MFMA GEMM -> lin [N][3120] ----
    {
        const int Kp = 1600, Nout = 3120, Npad = 3200;
        transpose_cast_kernel<<<dim3(Kp / 32, Npad / 32), 256, 0, stream>>>(W3, Wt, 1560, Nout, Kp, Npad);
        gemm_mfma_bf16<<<dim3(Npad / 128, N / 128), 256, 0, stream>>>(hbf2, Wt, linb, N, Nout, Kp, Nout);
        gat_tail(as3, ad3, b3, 1, 3120, 3120, 1, linb, hbf3, 3120);
    }

    // global max pool (bf16 in, bf16 padded out) + fc_g1 (MFMA split-K)
    {
        int tot = NB * 3200;
        pool_max_bf16_kernel<<<(tot + 255) / 256, 256, 0, stream>>>(hbf3, gbufb, NB, N / NB, 3120, 3200);
        head_gemm_mfma(gbufb, fc_g1_w, fc_g1_b, g1, NB, 1024, 3120, 3200, 5);
    }

    // ---- CNN branch (bufA free now) ----
    {
        conv_wt_all_kernel<<<(64 * 32 * 8 + 96 * 64 * 8 + 128 * 96 * 8 + 32 * 8000 + 255) / 256,
                             256, 0, stream>>>(cw2, cw3, cw4, cw1, wt2, wt3, wt4, wt1f);
        conv1_p1_kernel<<<dim3(NB, C1SPLIT), 256, 0, stream>>>(target, wt1f, Spart);
        conv1_p2_kernel<<<NB, 256, 0, stream>>>(Spart, emb_xt, cb1, act1);
        gemm_conv_bf16<32, 64, 114><<<dim3(1, NB), 256, 0, stream>>>(act1, wt2, cb2, act2);
        gemm_conv_bf16<64, 96, 107><<<dim3(1, NB), 256, 0, stream>>>(act2, wt3, cb3, act3);
        gemm_conv4_pool_bf16<<<dim3(1, NB), 256, 0, stream>>>(act3, wt4, cb4, xtb);
        head_gemm_mfma(xtb, fc1_xt_w, fc1_xt_b, xt1, NB, 1024, 4224, 4352, 4);
    }

    // ---- fully fused FC head (1024 threads: 16 waves/CU) ----
    fused_head_kernel<<<NB, 1024, 0, stream>>>(
        g1, xt1, fc_g2_w, fc_g2_b, fc2_xt_w, fc2_xt_b,
        fc1_w, fc1_b, fc2_w, fc2_b, out_w, out_b, out);
}